// Round 5
// baseline (171.347 us; speedup 1.0000x reference)
//
#include <hip/hip_runtime.h>

#define BS 16
#define NH 16
#define LQ 4096
#define DH 32

constexpr int SPLIT = 8;
constexpr int SCHUNK = LQ / SPLIT;          // 512 s per block = 8 stages x 64
constexpr size_t OUT_ELEMS = (size_t)BS * NH * LQ * DH;   // 33,554,432
constexpr int HDE = NH * DH * DH;           // 16384

// global -> LDS direct copy, 16 B per lane. dst is the WAVE-UNIFORM base;
// HW writes dst + lane*16. src is per-lane.
__device__ __forceinline__ void async_cp16(float* dst, const float* src) {
    __builtin_amdgcn_global_load_lds(
        (const __attribute__((address_space(1))) void*)src,
        (__attribute__((address_space(3))) void*)dst, 16, 0, 0);
}

__device__ __forceinline__ void fma4(float4& a, float s, const float4& v) {
    a.x = fmaf(s, v.x, a.x);
    a.y = fmaf(s, v.y, a.y);
    a.z = fmaf(s, v.z, a.z);
    a.w = fmaf(s, v.w, a.w);
}

// ---------------- Kernel A: partial K@V over an s-chunk ----------------
// 2048 blocks x 256 thr. T3 "minimum 2-phase": double-buffered 64-s stages via
// global_load_lds; ALL sync is plain __syncthreads() (emits vmcnt(0) lgkmcnt(0)
// before s_barrier -> drains the gll queue; no inline asm, no race surface).
// Next-stage glls issue BEFORE compute so HBM latency hides under compute+TLP.
// 32 KB LDS -> 5 blocks/CU. K staged [d][s-group] with XOR swizzle applied on
// the global SOURCE address (gll dest must stay linear); V staged linear [s][e].
__global__ __launch_bounds__(256, 5) void kv_partial(const float* __restrict__ k,
                                                     const float* __restrict__ v,
                                                     float* __restrict__ part) {
    __shared__ float lds[8192];             // [0,2048)=K0 [2048,4096)=K1 [4096,6144)=V0 [6144,8192)=V1
    const int tid  = threadIdx.x;
    const int wid  = tid >> 6;
    const int lane = tid & 63;
    const int p    = blockIdx.x & (SPLIT - 1);
    const int bh   = blockIdx.x >> 3;

    const int dgl = lane >> 3;              // 0..7
    const int d0  = dgl << 2;
    const int e0  = (lane & 7) << 2;

    const float* kb = k + (size_t)bh * DH * LQ;
    const float* vb = v + (size_t)bh * LQ * DH;
    const int s_blk = p * SCHUNK;

    // staging constants: wave issues K instrs {i0,i1} and V instrs {i0,i1}
    const int i0 = wid << 1;
    const int i1 = i0 + 1;
    // K instr i, lane l: writes kt + i*256 + 4l = row d = 4i + (l>>4), stored
    // group gs = l&15. Value needed there: K[d][4*(gs ^ i)] (swz(d)=d>>2=i).
    const size_t ksrc0 = (size_t)((i0 << 2) + (lane >> 4)) * LQ + (((lane & 15) ^ i0) << 2);
    const size_t ksrc1 = (size_t)((i1 << 2) + (lane >> 4)) * LQ + (((lane & 15) ^ i1) << 2);
    const int voff_l0 = (i0 << 8) + (lane << 2);
    const int voff_l1 = (i1 << 8) + (lane << 2);

    // compute offsets (constant across stages): per bi, K base and V base
    int koff[4], voff[4];
#pragma unroll
    for (int bi = 0; bi < 4; ++bi) {
        const int g = (wid << 2) + bi;                  // s-group 4g..4g+3 within stage
        koff[bi] = (d0 << 6) + (((g ^ dgl) & 15) << 2); // d0*64 + 4*(g^dgl)
        voff[bi] = (g << 7) + e0;                       // (4g)*32 + e0
    }

    float4 acc0 = {0,0,0,0}, acc1 = {0,0,0,0}, acc2 = {0,0,0,0}, acc3 = {0,0,0,0};

    // prologue: stage 0 into buffer 0, then full-drain barrier
    async_cp16(lds        + (i0 << 8), kb + ksrc0 + s_blk);
    async_cp16(lds        + (i1 << 8), kb + ksrc1 + s_blk);
    async_cp16(lds + 4096 + (i0 << 8), vb + ((size_t)s_blk << 5) + voff_l0);
    async_cp16(lds + 4096 + (i1 << 8), vb + ((size_t)s_blk << 5) + voff_l1);
    __syncthreads();

#pragma unroll
    for (int t = 0; t < 8; ++t) {
        float* kc = lds +        ((t & 1) << 11);
        float* vc = lds + 4096 + ((t & 1) << 11);
        // issue next stage into the other buffer BEFORE compute; the loads fly
        // during the compute phase and the next __syncthreads drains them.
        if (t < 7) {
            float* kn = lds +        (((t + 1) & 1) << 11);
            float* vn = lds + 4096 + (((t + 1) & 1) << 11);
            const int sb = s_blk + (t + 1) * 64;
            async_cp16(kn + (i0 << 8), kb + ksrc0 + sb);
            async_cp16(kn + (i1 << 8), kb + ksrc1 + sb);
            async_cp16(vn + (i0 << 8), vb + ((size_t)sb << 5) + voff_l0);
            async_cp16(vn + (i1 << 8), vb + ((size_t)sb << 5) + voff_l1);
        }

#pragma unroll
        for (int bi = 0; bi < 4; ++bi) {
            const float4 kq0 = *(const float4*)(kc + koff[bi]);
            const float4 kq1 = *(const float4*)(kc + koff[bi] + 64);
            const float4 kq2 = *(const float4*)(kc + koff[bi] + 128);
            const float4 kq3 = *(const float4*)(kc + koff[bi] + 192);
            const float4 vv0 = *(const float4*)(vc + voff[bi]);
            const float4 vv1 = *(const float4*)(vc + voff[bi] + 32);
            const float4 vv2 = *(const float4*)(vc + voff[bi] + 64);
            const float4 vv3 = *(const float4*)(vc + voff[bi] + 96);

            fma4(acc0, kq0.x, vv0); fma4(acc0, kq0.y, vv1); fma4(acc0, kq0.z, vv2); fma4(acc0, kq0.w, vv3);
            fma4(acc1, kq1.x, vv0); fma4(acc1, kq1.y, vv1); fma4(acc1, kq1.z, vv2); fma4(acc1, kq1.w, vv3);
            fma4(acc2, kq2.x, vv0); fma4(acc2, kq2.y, vv1); fma4(acc2, kq2.z, vv2); fma4(acc2, kq2.w, vv3);
            fma4(acc3, kq3.x, vv0); fma4(acc3, kq3.y, vv1); fma4(acc3, kq3.z, vv2); fma4(acc3, kq3.w, vv3);
        }
        // full drain + barrier: (a) stage t+1 gll writes have landed,
        // (b) every wave is done reading buf t&1 before t+1 overwrites it next iter.
        __syncthreads();
    }

    // cross-wave reduce: wave w -> lds[w*1024 + d*32 + e] (compute all done: last
    // __syncthreads above orders these writes after every wave's stage-7 reads)
    float* red = lds;
    *(float4*)(red + (wid << 10) + ((d0 + 0) << 5) + e0) = acc0;
    *(float4*)(red + (wid << 10) + ((d0 + 1) << 5) + e0) = acc1;
    *(float4*)(red + (wid << 10) + ((d0 + 2) << 5) + e0) = acc2;
    *(float4*)(red + (wid << 10) + ((d0 + 3) << 5) + e0) = acc3;
    __syncthreads();

    const int t4 = tid << 2;
    const float4 r0 = *(const float4*)(red + t4);
    const float4 r1 = *(const float4*)(red + 1024 + t4);
    const float4 r2 = *(const float4*)(red + 2048 + t4);
    const float4 r3 = *(const float4*)(red + 3072 + t4);
    float4 r;
    r.x = (r0.x + r1.x) + (r2.x + r3.x);
    r.y = (r0.y + r1.y) + (r2.y + r3.y);
    r.z = (r0.z + r1.z) + (r2.z + r3.z);
    r.w = (r0.w + r1.w) + (r2.w + r3.w);
    *(float4*)(part + ((size_t)p * (BS * NH) + bh) * 1024 + t4) = r;
}

// ---------------- Kernel B: reduce partials + softmax over batch axis ----------------
__global__ __launch_bounds__(256) void softmax_b(const float* __restrict__ part,
                                                 float* __restrict__ wts) {
    int idx = blockIdx.x * 256 + threadIdx.x;     // 0..16383 = h*1024 + d*32 + e

    float sc[BS];
#pragma unroll
    for (int b = 0; b < BS; ++b) {
        float s = 0.f;
#pragma unroll
        for (int pp = 0; pp < SPLIT; ++pp) {
            s += part[(((size_t)pp * BS * NH + (size_t)b * NH) << 10) + idx];
        }
        sc[b] = s * (1.0f / 64.0f);               // / sqrt(4096)
    }

    float m = sc[0];
#pragma unroll
    for (int b = 1; b < BS; ++b) m = fmaxf(m, sc[b]);
    float sum = 0.f;
#pragma unroll
    for (int b = 0; b < BS; ++b) { sc[b] = __expf(sc[b] - m); sum += sc[b]; }
    float inv = 1.0f / sum;
#pragma unroll
    for (int b = 0; b < BS; ++b) {
        wts[(size_t)b * HDE + idx] = sc[b] * inv;
    }
}

// ---------------- Kernel C: out = Q @ W ----------------
// 8192 blocks x 256 thr. Q tile staged in LDS (stride 36 -> conflict-free b128 reads),
// W column-block in 128 VGPRs. 1 ds_read_b128 per 16 FMA.
__global__ __launch_bounds__(256, 2) void qw(const float* __restrict__ q,
                                             const float* __restrict__ wts,
                                             float* __restrict__ out) {
    __shared__ float qs[128 * 36];
    const int blk = blockIdx.x;
    const int bh  = blk >> 5;
    const int lt  = blk & 31;
    const int tid = threadIdx.x;

    const float* qbase = q + ((size_t)bh * LQ + lt * 128) * DH;

#pragma unroll
    for (int pp = 0; pp < 4; ++pp) {
        const int idx = pp * 256 + tid;           // float4 index 0..1023
        const int row = idx >> 3;
        const int c4  = idx & 7;
        const float4 t = *(const float4*)(qbase + idx * 4);
        *(float4*)(qs + row * 36 + c4 * 4) = t;
    }

    const int lsub = tid >> 3;                    // 0..31
    const int e0   = (tid & 7) << 2;

    float4 Wf[32];
    const float* wbase = wts + (size_t)bh * (DH * DH) + e0;
#pragma unroll
    for (int d = 0; d < 32; ++d) Wf[d] = *(const float4*)(wbase + d * DH);

    __syncthreads();

    float* obase = out + ((size_t)bh * LQ + lt * 128) * DH;

#pragma unroll
    for (int r = 0; r < 4; ++r) {
        const int lr = lsub + r * 32;
        const float* qrow = qs + lr * 36;
        float4 acc = {0,0,0,0};
#pragma unroll
        for (int d4 = 0; d4 < 32; d4 += 4) {
            const float4 qv = *(const float4*)(qrow + d4);
            fma4(acc, qv.x, Wf[d4 + 0]);
            fma4(acc, qv.y, Wf[d4 + 1]);
            fma4(acc, qv.z, Wf[d4 + 2]);
            fma4(acc, qv.w, Wf[d4 + 3]);
        }
        *(float4*)(obase + (size_t)lr * DH + e0) = acc;
    }
}

extern "C" void kernel_launch(void* const* d_in, const int* in_sizes, int n_in,
                              void* d_out, int out_size, void* d_ws, size_t ws_size,
                              hipStream_t stream) {
    const float* q = (const float*)d_in[0];
    const float* k = (const float*)d_in[1];
    const float* v = (const float*)d_in[2];
    float* out  = (float*)d_out;
    float* wts  = out + OUT_ELEMS;          // attn_weights region of d_out
    float* part = (float*)d_ws;             // 8 MB of partials

    kv_partial<<<BS * NH * SPLIT, 256, 0, stream>>>(k, v, part);
    softmax_b<<<HDE / 256, 256, 0, stream>>>(part, wts);
    qw<<<BS * NH * (LQ / 128), 256, 0, stream>>>(q, wts, out);
}

// Round 7
// 160.245 us; speedup vs baseline: 1.0693x; 1.0693x over previous
//
#include <hip/hip_runtime.h>

#define BS 16
#define NH 16
#define LQ 4096
#define DH 32

constexpr int SPLIT = 8;
constexpr int SCHUNK = LQ / SPLIT;          // 512 s per block = 2 stages x 256
constexpr size_t OUT_ELEMS = (size_t)BS * NH * LQ * DH;   // 33,554,432
constexpr int HDE = NH * DH * DH;           // 16384

// global -> LDS direct copy, 16 B per lane. dst is the WAVE-UNIFORM base;
// HW writes dst + lane*16. src is per-lane.
__device__ __forceinline__ void async_cp16(float* dst, const float* src) {
    __builtin_amdgcn_global_load_lds(
        (const __attribute__((address_space(1))) void*)src,
        (__attribute__((address_space(3))) void*)dst, 16, 0, 0);
}

__device__ __forceinline__ void fma4(float4& a, float s, const float4& v) {
    a.x = fmaf(s, v.x, a.x);
    a.y = fmaf(s, v.y, a.y);
    a.z = fmaf(s, v.z, a.z);
    a.w = fmaf(s, v.w, a.w);
}

// ---------------- Kernel A: partial K@V over an s-chunk ----------------
// 2048 blocks x 256 thr. Sync-structure: proven __syncthreads-only discipline
// (counted-vmcnt pipelines failed 3x -> abandoned per m152). Per 256-s stage:
// 64 back-to-back glls fill the WHOLE 64 KB buffer (HBM latency paid once per
// fill, streaming BW after), ONE barrier, long uninterrupted compute. Single
// buffer, single use per stage -> no WAR hazards, no rotation. 4 barriers in
// total. 64 KB LDS -> 2 blocks/CU; cross-block TLP overlaps fill<->compute.
// K: row d = one gll (256 floats), stored slot l holds source s-group
// l ^ ((d>>2)&7)  (XOR on gll SOURCE addr; dest stays linear) -> ds_read_b128
// of rows d0..d0+3 at group g hits 8 distinct bank-clusters (conflict-free,
// 8-lane broadcast). V: linear [s][e], coalesced fills, conflict-free reads.
__global__ __launch_bounds__(256, 2) void kv_partial(const float* __restrict__ k,
                                                     const float* __restrict__ v,
                                                     float* __restrict__ part) {
    __shared__ float lds[16384];            // K[32][256] swizzled | V[256][32] linear
    const int tid  = threadIdx.x;
    const int wid  = tid >> 6;
    const int lane = tid & 63;
    const int p    = blockIdx.x & (SPLIT - 1);
    const int bh   = blockIdx.x >> 3;

    const int dgl = lane >> 3;              // 0..7
    const int d0  = dgl << 2;
    const int e0  = (lane & 7) << 2;

    const float* kb = k + (size_t)bh * DH * LQ;
    const float* vb = v + (size_t)bh * LQ * DH;
    const int s_blk = p * SCHUNK;

    float* kt = lds;                        // 8192 floats
    float* vt = lds + 8192;                 // 8192 floats

    float4 acc0 = {0,0,0,0}, acc1 = {0,0,0,0}, acc2 = {0,0,0,0}, acc3 = {0,0,0,0};

#pragma unroll
    for (int st = 0; st < 2; ++st) {
        const int sb = s_blk + (st << 8);   // stage's 256-s base

        // ---- fill: 16 glls per wave (8 K rows + 8 V segments) ----
#pragma unroll
        for (int i = 0; i < 8; ++i) {
            const int d = (wid << 3) + i;                  // K row this gll covers
            async_cp16(kt + (d << 8),
                       kb + (size_t)d * LQ + sb + ((lane ^ (d >> 2)) << 2));
            const int o = (((wid << 3) + i) << 8);         // V 256-float segment
            async_cp16(vt + o, vb + (((size_t)sb) << 5) + o + (lane << 2));
        }
        __syncthreads();                     // drains vmcnt(0): all 64 KB resident

        // ---- compute: wave w covers s-groups [16w, 16w+16) of this stage ----
#pragma unroll 4
        for (int gg = 0; gg < 16; ++gg) {
            const int g  = (wid << 4) + gg;
            const int ko = (g ^ dgl) << 2;                 // swizzled within-row offset
            const float4 kq0 = *(const float4*)(kt + ((d0 + 0) << 8) + ko);
            const float4 kq1 = *(const float4*)(kt + ((d0 + 1) << 8) + ko);
            const float4 kq2 = *(const float4*)(kt + ((d0 + 2) << 8) + ko);
            const float4 kq3 = *(const float4*)(kt + ((d0 + 3) << 8) + ko);
            const int vo = (g << 7) + e0;
            const float4 vv0 = *(const float4*)(vt + vo);
            const float4 vv1 = *(const float4*)(vt + vo + 32);
            const float4 vv2 = *(const float4*)(vt + vo + 64);
            const float4 vv3 = *(const float4*)(vt + vo + 96);

            fma4(acc0, kq0.x, vv0); fma4(acc0, kq0.y, vv1); fma4(acc0, kq0.z, vv2); fma4(acc0, kq0.w, vv3);
            fma4(acc1, kq1.x, vv0); fma4(acc1, kq1.y, vv1); fma4(acc1, kq1.z, vv2); fma4(acc1, kq1.w, vv3);
            fma4(acc2, kq2.x, vv0); fma4(acc2, kq2.y, vv1); fma4(acc2, kq2.z, vv2); fma4(acc2, kq2.w, vv3);
            fma4(acc3, kq3.x, vv0); fma4(acc3, kq3.y, vv1); fma4(acc3, kq3.z, vv2); fma4(acc3, kq3.w, vv3);
        }
        __syncthreads();                     // all reads done before refill/reduce
    }

    // cross-wave reduce: wave w -> lds[w*1024 + d*32 + e] (aliases K rows; the
    // last __syncthreads above ordered every wave's reads before these writes)
    float* red = lds;
    *(float4*)(red + (wid << 10) + ((d0 + 0) << 5) + e0) = acc0;
    *(float4*)(red + (wid << 10) + ((d0 + 1) << 5) + e0) = acc1;
    *(float4*)(red + (wid << 10) + ((d0 + 2) << 5) + e0) = acc2;
    *(float4*)(red + (wid << 10) + ((d0 + 3) << 5) + e0) = acc3;
    __syncthreads();

    const int t4 = tid << 2;
    const float4 r0 = *(const float4*)(red + t4);
    const float4 r1 = *(const float4*)(red + 1024 + t4);
    const float4 r2 = *(const float4*)(red + 2048 + t4);
    const float4 r3 = *(const float4*)(red + 3072 + t4);
    float4 r;
    r.x = (r0.x + r1.x) + (r2.x + r3.x);
    r.y = (r0.y + r1.y) + (r2.y + r3.y);
    r.z = (r0.z + r1.z) + (r2.z + r3.z);
    r.w = (r0.w + r1.w) + (r2.w + r3.w);
    *(float4*)(part + ((size_t)p * (BS * NH) + bh) * 1024 + t4) = r;
}

// ---------------- Kernel B: reduce partials + softmax over batch axis ----------------
__global__ __launch_bounds__(256) void softmax_b(const float* __restrict__ part,
                                                 float* __restrict__ wts) {
    int idx = blockIdx.x * 256 + threadIdx.x;     // 0..16383 = h*1024 + d*32 + e

    float sc[BS];
#pragma unroll
    for (int b = 0; b < BS; ++b) {
        float s = 0.f;
#pragma unroll
        for (int pp = 0; pp < SPLIT; ++pp) {
            s += part[(((size_t)pp * BS * NH + (size_t)b * NH) << 10) + idx];
        }
        sc[b] = s * (1.0f / 64.0f);               // / sqrt(4096)
    }

    float m = sc[0];
#pragma unroll
    for (int b = 1; b < BS; ++b) m = fmaxf(m, sc[b]);
    float sum = 0.f;
#pragma unroll
    for (int b = 0; b < BS; ++b) { sc[b] = __expf(sc[b] - m); sum += sc[b]; }
    float inv = 1.0f / sum;
#pragma unroll
    for (int b = 0; b < BS; ++b) {
        wts[(size_t)b * HDE + idx] = sc[b] * inv;
    }
}

// ---------------- Kernel C: out = Q @ W ----------------
// 8192 blocks x 256 thr. Q tile staged in LDS (stride 36 -> conflict-free b128 reads),
// W column-block in 128 VGPRs. 1 ds_read_b128 per 16 FMA.
__global__ __launch_bounds__(256, 2) void qw(const float* __restrict__ q,
                                             const float* __restrict__ wts,
                                             float* __restrict__ out) {
    __shared__ float qs[128 * 36];
    const int blk = blockIdx.x;
    const int bh  = blk >> 5;
    const int lt  = blk & 31;
    const int tid = threadIdx.x;

    const float* qbase = q + ((size_t)bh * LQ + lt * 128) * DH;

#pragma unroll
    for (int pp = 0; pp < 4; ++pp) {
        const int idx = pp * 256 + tid;           // float4 index 0..1023
        const int row = idx >> 3;
        const int c4  = idx & 7;
        const float4 t = *(const float4*)(qbase + idx * 4);
        *(float4*)(qs + row * 36 + c4 * 4) = t;
    }

    const int lsub = tid >> 3;                    // 0..31
    const int e0   = (tid & 7) << 2;

    float4 Wf[32];
    const float* wbase = wts + (size_t)bh * (DH * DH) + e0;
#pragma unroll
    for (int d = 0; d < 32; ++d) Wf[d] = *(const float4*)(wbase + d * DH);

    __syncthreads();

    float* obase = out + ((size_t)bh * LQ + lt * 128) * DH;

#pragma unroll
    for (int r = 0; r < 4; ++r) {
        const int lr = lsub + r * 32;
        const float* qrow = qs + lr * 36;
        float4 acc = {0,0,0,0};
#pragma unroll
        for (int d4 = 0; d4 < 32; d4 += 4) {
            const float4 qv = *(const float4*)(qrow + d4);
            fma4(acc, qv.x, Wf[d4 + 0]);
            fma4(acc, qv.y, Wf[d4 + 1]);
            fma4(acc, qv.z, Wf[d4 + 2]);
            fma4(acc, qv.w, Wf[d4 + 3]);
        }
        *(float4*)(obase + (size_t)lr * DH + e0) = acc;
    }
}

extern "C" void kernel_launch(void* const* d_in, const int* in_sizes, int n_in,
                              void* d_out, int out_size, void* d_ws, size_t ws_size,
                              hipStream_t stream) {
    const float* q = (const float*)d_in[0];
    const float* k = (const float*)d_in[1];
    const float* v = (const float*)d_in[2];
    float* out  = (float*)d_out;
    float* wts  = out + OUT_ELEMS;          // attn_weights region of d_out
    float* part = (float*)d_ws;             // 8 MB of partials

    kv_partial<<<BS * NH * SPLIT, 256, 0, stream>>>(k, v, part);
    softmax_b<<<HDE / 256, 256, 0, stream>>>(part, wts);
    qw<<<BS * NH * (LQ / 128), 256, 0, stream>>>(q, wts, out);
}